// Round 15
// baseline (662.472 us; speedup 1.0000x reference)
//
#include <hip/hip_runtime.h>
#include <math.h>

#define SEQ    4096
#define DIM    1024
#define NEXP   8
#define NSLOT  512
#define ES     4096
#define HID    4096
#define NB     2
#define RMS_SCALE 32.0f

typedef __attribute__((ext_vector_type(4))) float f32x4;
typedef __attribute__((ext_vector_type(8))) _Float16 f16x8;
typedef __attribute__((ext_vector_type(4))) unsigned short us4;

__device__ __forceinline__ unsigned short f2h(float f) {
    union { _Float16 h; unsigned short u; } c;
    c.h = (_Float16)f;
    return c.u;
}
__device__ __forceinline__ float h2f(unsigned short u) {
    union { unsigned short u; _Float16 h; } c;
    c.u = u;
    return (float)c.h;
}
__device__ __forceinline__ float gelu_exact(float x) {
    return 0.5f * x * (1.0f + erff(x * 0.70710678118654752f));
}

#define GLOAD_LDS16(gp, lp) \
    __builtin_amdgcn_global_load_lds((const __attribute__((address_space(1))) void*)(gp), \
                                     (__attribute__((address_space(3))) void*)(lp), 16, 0, 0)

__device__ __forceinline__ unsigned ldsoff(const void* p) {
    return (unsigned)(size_t)(const __attribute__((address_space(3))) void*)p;
}

#define DSR(dst, base, off) asm volatile("ds_read_b128 %0, %1 offset:" off : "=v"(dst) : "v"(base))
#define VM(n) asm volatile("s_waitcnt vmcnt(" #n ")" ::: "memory")
#define BAR __builtin_amdgcn_s_barrier()
#define SCB __builtin_amdgcn_sched_barrier(0)

// single required fence (rule #18): SCB between lgkmcnt(0) and MFMA
#define PH_OPEN  BAR; asm volatile("s_waitcnt lgkmcnt(0)" ::: "memory"); SCB; \
                 __builtin_amdgcn_s_setprio(1);
#define PH_CLOSE __builtin_amdgcn_s_setprio(0);

// ---------------- merged RMSNorm + fp16 split ----------------
__global__ void rmsnorm_both(const float* __restrict__ x, const float* __restrict__ ng,
                             const float* __restrict__ semb, const float* __restrict__ sg,
                             unsigned short* __restrict__ Acat, unsigned short* __restrict__ Bcat) {
    int row = blockIdx.x;
    int t = threadIdx.x;
    const bool isX = row < NB*SEQ;
    const float* in = isX ? x + (size_t)row * DIM : semb + (size_t)(row - NB*SEQ) * DIM;
    const float* gamma = isX ? ng : sg;
    unsigned short* rb = isX ? Acat + (size_t)row * 2048
                             : Bcat + (size_t)(row - NB*SEQ) * 2048;
    float4 v = reinterpret_cast<const float4*>(in)[t];
    float ss = v.x*v.x + v.y*v.y + v.z*v.z + v.w*v.w;
    #pragma unroll
    for (int off = 32; off >= 1; off >>= 1) ss += __shfl_down(ss, off, 64);
    __shared__ float red[4];
    if ((t & 63) == 0) red[t >> 6] = ss;
    __syncthreads();
    float inv = RMS_SCALE / fmaxf(sqrtf(red[0] + red[1] + red[2] + red[3]), 1e-12f);
    float4 g = reinterpret_cast<const float4*>(gamma)[t];
    float f[4] = {v.x*inv*g.x, v.y*inv*g.y, v.z*inv*g.z, v.w*inv*g.w};
    us4 hv, lv;
    #pragma unroll
    for (int q = 0; q < 4; ++q) {
        unsigned short h = f2h(f[q]);
        hv[q] = h;
        lv[q] = isX ? f2h(f[q] - h2f(h)) : h;
    }
    *reinterpret_cast<us4*>(&rb[t*4]) = hv;
    *reinterpret_cast<us4*>(&rb[1024 + t*4]) = lv;
}

// ---------------- merged max-partial reduce ----------------
__global__ void maxreduce_all(const float* __restrict__ rowpM, const float* __restrict__ colpM,
                              float* __restrict__ rmax, float* __restrict__ cmax) {
    int bx = blockIdx.x, t = threadIdx.x;
    if (bx < 32) {
        int row = bx * 256 + t;
        float m = -INFINITY;
        for (int p = 0; p < 64; ++p) m = fmaxf(m, rowpM[(size_t)p*8192 + row]);
        rmax[row] = m;
    } else {
        int fl = (bx - 32) * 256 + t;
        int b = fl >> 12, col = fl & 4095;
        float m = -INFINITY;
        for (int p = b*32; p < b*32 + 32; ++p) m = fmaxf(m, colpM[(size_t)p*4096 + col]);
        cmax[fl] = m;
    }
}

// ---------------- merged sum-partial reduce ----------------
__global__ void sumreduce_all(const float* __restrict__ rowpS, const float* __restrict__ colpS,
                              float* __restrict__ rinv, float* __restrict__ cinv) {
    int bx = blockIdx.x, t = threadIdx.x;
    const float* src = (bx < 32) ? rowpS : colpS;
    float* dst = (bx < 32) ? rinv : cinv;
    int fl = (bx & 31) * 256 + t;
    float s = 0.f;
    for (int p = 0; p < 128; ++p) s += src[(size_t)p*8192 + fl];
    dst[fl] = 1.0f / s;
}

// ---------------- fused weights pass ----------------
__global__ void make_weights(const float* __restrict__ logits,
                             const float* __restrict__ cmax, const float* __restrict__ rmax,
                             unsigned short* __restrict__ comb, unsigned short* __restrict__ dispT,
                             float* __restrict__ rowpS, float* __restrict__ colpS) {
    int b = blockIdx.z;
    const float* L = logits + (size_t)b * SEQ * ES;
    int n0 = blockIdx.y * 32, e0 = blockIdx.x * 32;
    int t = threadIdx.x;
    int r = t >> 3, c4 = (t & 7) * 4;
    __shared__ unsigned short tile[32][36];
    float4 v = *reinterpret_cast<const float4*>(&L[(size_t)(n0 + r) * ES + e0 + c4]);
    float rm = rmax[b*SEQ + n0 + r];
    float vv[4] = {v.x, v.y, v.z, v.w};
    us4 cb;
    float rs = 0.f;
    #pragma unroll
    for (int q = 0; q < 4; ++q) {
        cb[q] = f2h(__expf(vv[q] - rm));
        rs += h2f(cb[q]);
        float dv = __expf(vv[q] - cmax[b*ES + e0 + c4 + q]);
        tile[c4 + q][r] = f2h(dv);
    }
    *reinterpret_cast<us4*>(&comb[(size_t)b*SEQ*ES + (size_t)(n0 + r)*ES + e0 + c4]) = cb;
    rs += __shfl_xor(rs, 1, 64);
    rs += __shfl_xor(rs, 2, 64);
    rs += __shfl_xor(rs, 4, 64);
    if ((t & 7) == 0)
        rowpS[(size_t)blockIdx.x * 8192 + b*SEQ + n0 + r] = rs;
    __syncthreads();
    us4 o = *reinterpret_cast<us4*>(&tile[t >> 3][(t & 7) * 4]);
    *reinterpret_cast<us4*>(&dispT[(size_t)b*ES*SEQ + (size_t)(e0 + (t >> 3))*SEQ + n0 + (t & 7)*4]) = o;
    float cs = h2f(o[0]) + h2f(o[1]) + h2f(o[2]) + h2f(o[3]);
    cs += __shfl_xor(cs, 1, 64);
    cs += __shfl_xor(cs, 2, 64);
    cs += __shfl_xor(cs, 4, 64);
    if ((t & 7) == 0)
        colpS[(size_t)blockIdx.y * 8192 + b*ES + e0 + (t >> 3)] = cs;
}

// ---------------- 16-bit transpose ----------------
__global__ void transpose_b16(const unsigned short* __restrict__ src, unsigned short* __restrict__ dst,
                              int sld, int dld, long sStride, long dStride) {
    int z = blockIdx.z;
    const unsigned short* S = src + (size_t)z * sStride;
    unsigned short* D = dst + (size_t)z * dStride;
    int r0 = blockIdx.y * 32, c0 = blockIdx.x * 32;
    int t = threadIdx.x;
    __shared__ unsigned short tile[32][36];
    us4 v = *reinterpret_cast<const us4*>(&S[(size_t)(r0 + (t>>3)) * sld + c0 + (t&7)*4]);
    #pragma unroll
    for (int q = 0; q < 4; ++q) tile[(t&7)*4 + q][t>>3] = v[q];
    __syncthreads();
    us4 o = *reinterpret_cast<us4*>(&tile[t >> 3][(t & 7) * 4]);
    *reinterpret_cast<us4*>(&D[(size_t)(c0 + (t>>3)) * dld + r0 + (t&7)*4]) = o;
}

// ---------------- merged f32 -> fp16 weight transposes (w1 and w2) ----------------
// blocks 0..32767:     w1 [e][1024][4096] -> w1T [e][4096][1024]   (4096 tiles/expert)
// blocks 32768..65535: w2 [e][4096][1024] -> w2T [e][1024][4096]   (4096 tiles/expert)
__global__ void transpose_weights(const float* __restrict__ w1, unsigned short* __restrict__ w1T,
                                  const float* __restrict__ w2, unsigned short* __restrict__ w2T) {
    int bid = blockIdx.x;
    const bool isW1 = bid < 32768;
    int lb = isW1 ? bid : bid - 32768;
    int z = lb >> 12;                // expert (4096 tiles/expert)
    int tix = lb & 4095;
    const float* S;
    unsigned short* D;
    int sld, dld, r0, c0;
    if (isW1) {
        sld = HID; dld = DIM;
        S = w1 + (size_t)z * DIM * HID;
        D = w1T + (size_t)z * HID * DIM;
        r0 = (tix >> 7) * 32;        // 0..31 -> row tile over 1024
        c0 = (tix & 127) * 32;       // 0..127 -> col tile over 4096
    } else {
        sld = DIM; dld = HID;
        S = w2 + (size_t)z * HID * DIM;
        D = w2T + (size_t)z * DIM * HID;
        r0 = (tix >> 5) * 32;        // 0..127 -> row tile over 4096
        c0 = (tix & 31) * 32;        // 0..31 -> col tile over 1024
    }
    int t = threadIdx.x;
    __shared__ unsigned short tile[32][36];
    float4 v = *reinterpret_cast<const float4*>(&S[(size_t)(r0 + (t>>3)) * sld + c0 + (t&7)*4]);
    float vv[4] = {v.x, v.y, v.z, v.w};
    #pragma unroll
    for (int q = 0; q < 4; ++q) tile[(t&7)*4 + q][t>>3] = f2h(vv[q]);
    __syncthreads();
    us4 o = *reinterpret_cast<us4*>(&tile[t >> 3][(t & 7) * 4]);
    *reinterpret_cast<us4*>(&D[(size_t)(c0 + (t>>3)) * dld + r0 + (t&7)*4]) = o;
}

// ================= 256x256 8-phase MFMA GEMM — r4 core, fp16 =================
template<int EPI, int OM, int STATS>
__global__ __launch_bounds__(512, 2)
void mfma_gemm256(const unsigned short* __restrict__ A, const unsigned short* __restrict__ B,
                  void* __restrict__ Cv, const float* __restrict__ bias,
                  int N, int K, int lda, int ldb, int ldc,
                  long aStride, long bStride, long cStride, int bMod,
                  float* __restrict__ rowpM, float* __restrict__ colpM) {
    __shared__ unsigned short lds[65536];
    const int t = threadIdx.x;
    const int lane = t & 63, wave = t >> 6;
    const int wr = wave >> 2, wc = wave & 3;
    const int z = blockIdx.z, zb = z % bMod;
    const unsigned short* Ab = A + (size_t)z * aStride;
    const unsigned short* Bb = B + (size_t)zb * bStride;
    const int gx = gridDim.x;
    int flat = blockIdx.x + blockIdx.y * gx;
    const int cpx = (gx * gridDim.y) >> 3;
    flat = (flat & 7) * cpx + (flat >> 3);
    const int m0 = (flat / gx) * 256, n0 = (flat % gx) * 256;

    const int sr = t >> 3;
    const int sg = (t & 7) ^ (sr & 7);
    const unsigned short* gA = Ab + (size_t)(m0 + sr) * lda + sg * 8;
    const unsigned short* gB = Bb + (size_t)(n0 + sr) * ldb + sg * 8;
    unsigned short* ldsw = lds + wave * 512;

    const int lr = lane & 15, lk = lane >> 4;
    const unsigned sw0 = (unsigned)(((lk)     ^ (lr & 7)) << 4);
    const unsigned sw1 = (unsigned)(((4 + lk) ^ (lr & 7)) << 4);
    const unsigned l0  = ldsoff(lds);
    const unsigned arow = (unsigned)((wr*128 + lr) * 128);
    const unsigned brow = (unsigned)((wc*64  + lr) * 128);
    const unsigned ab00 = l0 + arow + sw0,          ab10 = l0 + arow + sw1;
    const unsigned bb00 = l0 + 32768 + brow + sw0,  bb10 = l0 + 32768 + brow + sw1;
    const unsigned ab01 = ab00 + 65536, ab11 = ab10 + 65536;
    const unsigned bb01 = bb00 + 65536, bb11 = bb10 + 65536;

    #define STAGE_A(buf, half, tt) do { \
        const unsigned short* _g = gA + (size_t)((half)*128) * lda + (size_t)(tt)*64; \
        unsigned short* _l = ldsw + (buf)*32768 + (half)*8192; \
        GLOAD_LDS16(_g, _l); \
        GLOAD_LDS16(_g + (size_t)64*lda, _l + 4096); } while(0)
    #define STAGE_B(buf, half, tt) do { \
        const unsigned short* _g = gB + (size_t)((half)*128) * ldb + (size_t)(tt)*64; \
        unsigned short* _l = ldsw + (buf)*32768 + 16384 + (half)*8192; \
        GLOAD_LDS16(_g, _l); \
        GLOAD_LDS16(_g + (size_t)64*ldb, _l + 4096); } while(0)

    #define MFMA16(MB, CN) \
        _Pragma("unroll") \
        for (int m = 0; m < 4; ++m) { \
            _Pragma("unroll") \
            for (int n = 0; n < 2; ++n) { \
                acc[(MB)+m][(CN)+n] = __builtin_amdgcn_mfma_f32_16x16x32_f16(a0[m], b0[(CN)+n], acc[(MB)+m][(CN)+n], 0, 0, 0); \
                acc[(MB)+m][(CN)+n] = __builtin_amdgcn_mfma_f32_16x16x32_f16(a1[m], b1[(CN)+n], acc[(MB)+m][(CN)+n], 0, 0, 0); \
            } \
        }

    f32x4 acc[8][4] = {};
    f16x8 a0[4], a1[4], b0[4], b1[4];
    const int NT = K / 64;

    STAGE_B(0, 0, 0); STAGE_B(0, 1, 0);
    STAGE_A(0, 0, 0); STAGE_A(0, 1, 0);
    STAGE_B(1, 0, 1); STAGE_B(1, 1, 1);
    VM(4); BAR;

    for (int tt = 0; tt < NT; tt += 2) {
        const bool pf = (tt + 2 < NT);
        // P1
        DSR(a0[0], ab00, "0");    DSR(a0[1], ab00, "2048");
        DSR(a0[2], ab00, "4096"); DSR(a0[3], ab00, "6144");
        DSR(a1[0], ab10, "0");    DSR(a1[1], ab10, "2048");
        DSR(a1[2], ab10, "4096"); DSR(a1[3], ab10, "6144");
        DSR(b0[0], bb00, "0");    DSR(b0[1], bb00, "2048");
        DSR(b1[0], bb10, "0");    DSR(b1[1], bb10, "2048");
        STAGE_A(1, 0, tt+1);
        PH_OPEN MFMA16(0, 0) PH_CLOSE
        BAR;
        // P2
        DSR(b0[2], bb00, "4096"); DSR(b0[3], bb00, "6144");
        DSR(b1[2], bb10, "4096"); DSR(b1[3], bb10, "6144");
        STAGE_A(1, 1, tt+1);
        PH_OPEN MFMA16(0, 2) PH_CLOSE
        BAR;
        // P3
        DSR(a0[0], ab00, "8192");  DSR(a0[1], ab00, "10240");
        DSR(a0[2], ab00, "12288"); DSR(a0[3], ab00, "14336");
        DSR(a1[0], ab10, "8192");  DSR(a1[1], ab10, "10240");
        DSR(a1[2], ab10, "12288"); DSR(a1[3], ab10, "14336");
        if (pf) STAGE_B(0, 0, tt+2);
        PH_OPEN MFMA16(4, 0) PH_CLOSE
        BAR;
        // P4 + wait
        if (pf) STAGE_B(0, 1, tt+2);
        PH_OPEN MFMA16(4, 2) PH_CLOSE
        if (pf) { VM(4); } else { VM(0); }
        BAR;
        // P5
        DSR(a0[0], ab01, "0");    DSR(a0[1], ab01, "2048");
        DSR(a0[2], ab01, "4096"); DSR(a0[3], ab01, "6144");
        DSR(a1[0], ab11, "0");    DSR(a1[1], ab11, "2048");
        DSR(a1[2], ab11, "4096"); DSR(a1[3], ab11, "6144");
        DSR(b0[0], bb01, "0");    DSR(b0[1], bb01, "2048");
        DSR(b1[0], bb11, "0");    DSR(b1[1], bb11, "2048");
        if (pf) STAGE_A(0, 0, tt+2);
        PH_OPEN MFMA16(0, 0) PH_CLOSE
        BAR;
        // P6
        DSR(b0[2], bb01, "4096"); DSR(b0[3], bb01, "6144");
        DSR(b1[2], bb11, "4096"); DSR(b1[3], bb11, "6144");
        if (pf) STAGE_A(0, 1, tt+2);
        PH_OPEN MFMA16(0, 2) PH_CLOSE
        BAR;
        // P7
        DSR(a0[0], ab01, "8192");  DSR(a0[1], ab01, "10240");
        DSR(a0[2], ab01, "12288"); DSR(a0[3], ab01, "14336");
        DSR(a1[0], ab11, "8192");  DSR(a1[1], ab11, "10240");
        DSR(a1[2], ab11, "12288"); DSR(a1[3], ab11, "14336");
        if (pf) STAGE_B(1, 0, tt+3);
        PH_OPEN MFMA16(4, 0) PH_CLOSE
        BAR;
        // P8 + wait
        if (pf) STAGE_B(1, 1, tt+3);
        PH_OPEN MFMA16(4, 2) PH_CLOSE
        if (pf) { VM(4); } else { VM(0); }
        BAR;
    }

    if (STATS) {
        #pragma unroll
        for (int f = 0; f < 8; ++f) {
            #pragma unroll
            for (int r = 0; r < 4; ++r) {
                float m = fmaxf(fmaxf(acc[f][0][r], acc[f][1][r]), fmaxf(acc[f][2][r], acc[f][3][r]));
                #pragma unroll
                for (int msk = 1; msk <= 8; msk <<= 1) m = fmaxf(m, __shfl_xor(m, msk, 64));
                if ((lane & 15) == 0) {
                    int row = m0 + wr*128 + f*16 + (lane>>4)*4 + r;
                    int slot = (n0 >> 6) + wc;
                    rowpM[(size_t)slot*8192 + row] = m;
                }
            }
        }
        #pragma unroll
        for (int n = 0; n < 4; ++n) {
            float m = -INFINITY;
            #pragma unroll
            for (int f = 0; f < 8; ++f)
                #pragma unroll
                for (int r = 0; r < 4; ++r) m = fmaxf(m, acc[f][n][r]);
            m = fmaxf(m, __shfl_xor(m, 16, 64));
            m = fmaxf(m, __shfl_xor(m, 32, 64));
            if ((lane >> 4) == 0) {
                int col = n0 + wc*64 + n*16 + lane;
                int slot = (m0 >> 7) + wr;
                colpM[(size_t)slot*4096 + col] = m;
            }
        }
    }

    const float* bz = (EPI != 0) ? bias + (size_t)zb * N : nullptr;
    long coff = (long)z * cStride;
    int rbase = (lane >> 4) * 4;
    int cbase = lane & 15;
    #pragma unroll
    for (int f = 0; f < 8; ++f) {
        #pragma unroll
        for (int n = 0; n < 4; ++n) {
            int col  = n0 + wc*64 + n*16 + cbase;
            int row0 = m0 + wr*128 + f*16 + rbase;
            float bv = (EPI != 0) ? bz[col] : 0.f;
            float vals[4];
            #pragma unroll
            for (int r = 0; r < 4; ++r) {
                float v = acc[f][n][r] + bv;
                if (EPI == 2) v = gelu_exact(v);
                vals[r] = v;
            }
            if (OM == 0) {
                float* C = (float*)Cv + coff;
                #pragma unroll
                for (int r = 0; r < 4; ++r) C[(size_t)(row0 + r) * ldc + col] = vals[r];
            } else {
                unsigned short* C = (unsigned short*)Cv + coff;
                #pragma unroll
                for (int r = 0; r < 4; ++r) C[(size_t)(row0 + r) * ldc + col] = f2h(vals[r]);
            }
        }
    }
    #undef STAGE_A
    #undef STAGE_B
    #undef MFMA16
}

// ================= 256x128 8-phase MFMA GEMM — fp16, quad halves, vmcnt(4)@P4/P8 ==========
template<int EPI, int OM, int SC>
__global__ __launch_bounds__(512, 2)
void mfma_gemmX(const unsigned short* __restrict__ A, const unsigned short* __restrict__ B,
                void* __restrict__ Cv, const float* __restrict__ bias,
                int N, int K, int lda, int ldb, int ldc,
                long aStride, long bStride, long cStride, long cStrideE, int bMod,
                const float* __restrict__ svec) {
    __shared__ unsigned short lds[49152];   // 96 KB
    const int t = threadIdx.x;
    const int lane = t & 63, wave = t >> 6;
    const int wr = wave >> 2, wc = wave & 3;
    const int z = blockIdx.z, zb = z % bMod;
    const unsigned short* Ab = A + (size_t)z * aStride;
    const unsigned short* Bb = B + (size_t)zb * bStride;
    const int gx = gridDim.x;
    int flat = blockIdx.x + blockIdx.y * gx;
    const int cpx = (gx * gridDim.y) >> 3;
    flat = (flat & 7) * cpx + (flat >> 3);
    const int m0 = (flat / gx) * 256, n0 = (flat % gx) * 128;

    const int sr = t >> 3;
    const int sg = (t & 7) ^ (sr & 7);
    const unsigned short* gA = Ab + (size_t)(m0 + sr) * lda + sg * 8;
    const unsigned short* gB = Bb + (size_t)(n0 + sr) * ldb + sg * 8;
    unsigned short* ldsw = lds + wave * 512;

    const int lr = lane & 15, lk = lane >> 4;
    const unsigned g0 = (unsigned)(((lk)     ^ (lr & 7)) << 4);
    const unsigned g1 = (unsigned)(((4 + lk) ^ (lr & 7)) << 4);
    const unsigned l0 = ldsoff(lds);
    const unsigned arow = (unsigned)((wr*64 + lr) * 128);
    const unsigned brow = (unsigned)((wc*32 + lr) * 128);
    const unsigned ax00 = l0 + arow + g0,          ax10 = l0 + arow + g1;
    const unsigned bx00 = l0 + 32768 + brow + g0,  bx10 = l0 + 32768 + brow + g1;
    const unsigned ax01 = ax00 + 49152, ax11 = ax10 + 49152;
    const unsigned bx01 = bx00 + 49152, bx11 = bx10 + 49152;

    #define STAGE_AX(buf, quad, tt) do { \
        const unsigned short* _g = gA + (size_t)((quad)*64) * lda + (size_t)(tt)*64; \
        unsigned short* _l = ldsw + (buf)*24576 + (quad)*8192; \
        GLOAD_LDS16(_g, _l); \
        GLOAD_LDS16(_g + (size_t)128*lda, _l + 4096); } while(0)
    #define STAGE_BX(buf, tt) do { \
        const unsigned short* _g = gB + (size_t)(tt)*64; \
        unsigned short* _l = ldsw + (buf)*24576 + 16384; \
        GLOAD_LDS16(_g, _l); \
        GLOAD_LDS16(_g + (size_t)64*ldb, _l + 4096); } while(0)

    #define MFMA8(MB, AR, BR) \
        _Pragma("unroll") \
        for (int m = 0; m < 4; ++m) { \
            _Pragma("unroll") \
            for (int n = 0; n < 2; ++n) { \
                acc[(MB)+m][n] = __builtin_amdgcn_mfma_f32_16x16x32_f16(AR[m], BR[n], acc[(MB)+m][n], 0, 0, 0); \
            } \
        }

    f32x4 acc[8][2] = {};
    f16x8 a0[4], a1[4], b0[2], b1[2];
    const int NT = K / 64;

    STAGE_AX(0, 0, 0); STAGE_BX(0, 0); STAGE_AX(0, 1, 0);
    STAGE_AX(1, 0, 1); STAGE_BX(1, 1);
    VM(0); BAR;

    for (int tt = 0; tt < NT; tt += 2) {
        const bool pf2 = (tt + 2 < NT);
        const bool pf3 = (tt + 3 < NT);
        // P1
        DSR(a0[0], ax00, "0");    DSR(a0[1], ax00, "2048");
        DSR(a0[2], ax00, "4096"); DSR(a0[3], ax00, "6144");
        DSR(b0[0], bx00, "0");    DSR(b0[1], bx00, "2048");
        STAGE_AX(1, 1, tt+1);
        PH_OPEN MFMA8(0, a0, b0) PH_CLOSE
        BAR;
        // P2
        DSR(a1[0], ax10, "0");    DSR(a1[1], ax10, "2048");
        DSR(a1[2], ax10, "4096"); DSR(a1[3], ax10, "6144");
        DSR(b1[0], bx10, "0");    DSR(b1[1], bx10, "2048");
        PH_OPEN MFMA8(0, a1, b1) PH_CLOSE
        BAR;
        // P3
        DSR(a0[0], ax00, "16384"); DSR(a0[1], ax00, "18432");
        DSR(a0[2], ax00, "20480"); DSR(a0[3], ax00, "22528");
        if (pf2) STAGE_AX(0, 0, tt+2);
        PH_OPEN MFMA8(4, a0, b0) PH_CLOSE
        BAR;
        // P4 + wait
        DSR(a1[0], ax10, "16384"); DSR(a1[1], ax10, "18432");
        DSR(a1[2], ax10, "20480"); DSR(a1[3], ax10, "22528");
        if (pf2) STAGE_BX(0, tt+2);
        PH_OPEN MFMA8(4, a1, b1) PH_CLOSE
        if (pf2) { VM(4); } else { VM(0); }
        BAR;
        // P5
        DSR(a0[0], ax01, "0");    DSR(a0[1], ax01, "2048");
        DSR(a0[2], ax01, "4096"); DSR(a0[3], ax01, "6144");
        DSR(b0[0], bx01, "0");    DSR(b0[1], bx01, "2048");
        if (pf2) STAGE_AX(0, 1, tt+2);
        PH_OPEN MFMA8(0, a0, b0) PH_CLOSE
        BAR;
        // P6
        DSR(a1[0], ax11, "0");    DSR(a1[1], ax11, "2048");
        DSR(a1[2], ax11, "4096"); DSR(a1[3], ax11, "6144");
        DSR(b1[0], bx11, "0");    DSR(b1[1], bx11, "2048");
        PH_OPEN MFMA8(0, a1, b1) PH_CLOSE
        BAR;
        // P7
        DSR(a0[0], ax01, "16384"); DSR(a0[1], ax01, "18432");
        DSR(a0[2], ax01, "20480"); DSR(a0[3], ax01, "22528");
        if (pf3) STAGE_AX(1, 0, tt+3);
        PH_OPEN MFMA8(4, a0, b0) PH_CLOSE
        BAR;
        // P8 + wait
        DSR(a1[0], ax11, "16384"); DSR(a1[1], ax11, "18432");
        DSR(a1[2], ax11, "20480"); DSR(a1[3], ax11, "22528");
        if (pf3) STAGE_BX(1, tt+3);
        PH_OPEN MFMA8(4, a1, b1) PH_CLOSE
        if (pf3) { VM(4); } else { VM(0); }
        BAR;
    }

    const float* bz = (EPI != 0) ? bias + (size_t)zb * N : nullptr;
    const float* sv = SC ? svec + (size_t)z * 4096 : nullptr;
    long coff = (long)z * cStride + (long)zb * cStrideE;
    int rbase = (lane >> 4) * 4;
    int cbase = lane & 15;
    #pragma unroll
    for (int f = 0; f < 8; ++f) {
        #pragma unroll
        for (int n = 0; n < 2; ++n) {
            int col  = n0 + wc*32 + n*16 + cbase;
            int row0 = m0 + wr*128 + f*16 + rbase;
            float bv = (EPI != 0) ? bz[col] : 0.f;
            float vals[4];
            #pragma unroll
            for (int r = 0; r < 4; ++r) {
                float v = acc[f][n][r] + bv;
                if (SC) v *= sv[row0 + r];
                if (EPI == 2) v = gelu_exact(v);
                vals[r] = v;
            }
            if (OM == 0) {
                float* C = (float*)Cv + coff;
                #pragma unroll
                for (int r = 0; r < 4; ++r) C[(size_t)(row0 + r) * ldc + col] = vals[r];
            } else if (OM == 1) {
                unsigned short* C = (unsigned short*)Cv + coff;
                #pragma unroll
                for (int r = 0; r < 4; ++r) C[(size_t)(row0 + r) * ldc + col] = f2h(vals[r]);
            } else {
                unsigned short* C = (unsigned short*)Cv + coff;
                us4 o;
                #pragma unroll
                for (int r = 0; r < 4; ++r) o[r] = f2h(vals[r]);
                *reinterpret_cast<us4*>(&C[(size_t)col * ldc + row0]) = o;
            }
        }
    }
    #undef STAGE_AX
    #undef STAGE_BX
    #undef MFMA8
}

extern "C" void kernel_launch(void* const* d_in, const int* in_sizes, int n_in,
                              void* d_out, int out_size, void* d_ws, size_t ws_size,
                              hipStream_t stream) {
    const float* x    = (const float*)d_in[0];
    const float* ng   = (const float*)d_in[1];
    const float* sg   = (const float*)d_in[2];
    const float* semb = (const float*)d_in[3];
    const float* w1   = (const float*)d_in[4];
    const float* b1   = (const float*)d_in[5];
    const float* w2   = (const float*)d_in[6];
    const float* b2   = (const float*)d_in[7];
    float* out = (float*)d_out;

    char* base = (char*)d_ws;
    unsigned short* Acat  = (unsigned short*)(base);               // [8192][2048] fp16 [hi|lo]
    unsigned short* Bcat  = (unsigned short*)(base + 33554432);    // [4096][2048] fp16 [hi|hi]
    unsigned short* dispT = (unsigned short*)(base);               // [2][4096][4096] (step5+)
    float*          logits= (float*)(base + 75497472);             // [2][4096][4096] f32
    unsigned short* hbuf  = (unsigned short*)(base + 75497472);    // [16][512][4096] fp16 (step9+)
    unsigned short* w1T   = (unsigned short*)(base + 142606336);   // [8][4096][1024] fp16 (step7+)
    unsigned short* xnT   = (unsigned short*)(base + 209715200);   // [2][1024][4096]
    unsigned short* comb  = (unsigned short*)(base + 226492416);   // [2][4096][4096]
    unsigned short* slots = (unsigned short*)(base + 293601280);   // [2][4096][1024]
    unsigned short* eoT   = (unsigned short*)(base + 293601280);   // [2][1024][4096]
    float* rowpM = (float*)(base + 226492416);        // (comb region, dead before step 5)
    float* colpM = rowpM + 64*8192;
    float* rmax  = (float*)(base + 310378496);
    float* rinv  = rmax + 8192;
    float* cmax  = rinv + 8192;
    float* cinv  = cmax + 8192;
    float* rowpS = cinv + 8192;                       // 4MB, ends ~314.7MB
    float* colpS = rowpS + 128*8192;                  // 4MB, ends ~318.9MB
    // w2T in tail region: [318963712, 386072576) — disjoint from colpS and < 386.5MB proven
    unsigned short* w2Tsafe = (unsigned short*)(base + 318963712);

    // 1. merged RMSNorm + fp16 split
    rmsnorm_both<<<NB*SEQ + NEXP*NSLOT, 256, 0, stream>>>(x, ng, semb, sg, Acat, Bcat);

    // 2. xnT[b][d][n]
    transpose_b16<<<dim3(DIM/32, SEQ/32, NB), 256, 0, stream>>>(
        Acat, xnT, 2048, SEQ, (long)SEQ*2048, (long)DIM*SEQ);

    // 3. logits = [x_hi|x_lo] @ [s_hi|s_hi]^T (K=2048) + max partials
    mfma_gemm256<0,0,1><<<dim3(ES/256, (NB*SEQ)/256, 1), 512, 0, stream>>>(
        Acat, Bcat, logits, nullptr, ES, 2048, 2048, 2048, ES,
        0L, 0L, 0L, 1, rowpM, colpM);

    // 4. merged max reductions
    maxreduce_all<<<64, 256, 0, stream>>>(rowpM, colpM, rmax, cmax);

    // 5. comb_u + dispT_u + sum partials
    make_weights<<<dim3(ES/32, SEQ/32, NB), 256, 0, stream>>>(
        logits, cmax, rmax, comb, dispT, rowpS, colpS);

    // 6. merged sum reductions
    sumreduce_all<<<64, 256, 0, stream>>>(rowpS, colpS, rinv, cinv);

    // 7. merged weight transposes: w1T (logits region, dead) + w2T (tail region)
    transpose_weights<<<65536, 256, 0, stream>>>(w1, w1T, w2, w2Tsafe);

    // 8. slots = (dispT_u @ xnT^T) * cinv[es]
    mfma_gemmX<0,1,1><<<dim3(DIM/128, ES/256, NB), 512, 0, stream>>>(
        dispT, xnT, slots, nullptr, DIM, SEQ, SEQ, SEQ, DIM,
        (long)ES*SEQ, (long)DIM*SEQ, (long)ES*DIM, 0L, NB, cinv);

    // 9. FF1: h = gelu(slots @ w1T^T + b1)
    mfma_gemm256<2,1,0><<<dim3(HID/256, NSLOT/256, NB*NEXP), 512, 0, stream>>>(
        slots, w1T, hbuf, b1, HID, DIM, DIM, DIM, HID,
        (long)NSLOT*DIM, (long)HID*DIM, (long)NSLOT*HID, NEXP,
        nullptr, nullptr);

    // 10. FF2: eoT = (h @ w2T^T + b2)^T
    mfma_gemmX<1,2,0><<<dim3(DIM/128, NSLOT/256, NB*NEXP), 512, 0, stream>>>(
        hbuf, w2Tsafe, eoT, b2, DIM, HID, HID, HID, ES,
        (long)NSLOT*HID, (long)DIM*HID, (long)(DIM*ES/NEXP), (long)(NSLOT - DIM*ES/NEXP), NEXP,
        nullptr);

    // 11. out = (comb_u @ eoT^T) * rinv[n]
    mfma_gemmX<0,0,1><<<dim3(DIM/128, SEQ/256, NB), 512, 0, stream>>>(
        comb, eoT, out, nullptr, DIM, ES, ES, ES, DIM,
        (long)SEQ*ES, (long)DIM*ES, (long)SEQ*DIM, 0L, NB, rinv);
}

// Round 17
// 648.739 us; speedup vs baseline: 1.0212x; 1.0212x over previous
//
#include <hip/hip_runtime.h>
#include <math.h>

#define SEQ    4096
#define DIM    1024
#define NEXP   8
#define NSLOT  512
#define ES     4096
#define HID    4096
#define NB     2
#define RMS_SCALE 32.0f

typedef __attribute__((ext_vector_type(4))) float f32x4;
typedef __attribute__((ext_vector_type(8))) _Float16 f16x8;
typedef __attribute__((ext_vector_type(4))) unsigned short us4;

__device__ __forceinline__ unsigned short f2h(float f) {
    union { _Float16 h; unsigned short u; } c;
    c.h = (_Float16)f;
    return c.u;
}
__device__ __forceinline__ float h2f(unsigned short u) {
    union { unsigned short u; _Float16 h; } c;
    c.u = u;
    return (float)c.h;
}
__device__ __forceinline__ float gelu_exact(float x) {
    return 0.5f * x * (1.0f + erff(x * 0.70710678118654752f));
}

#define GLOAD_LDS16(gp, lp) \
    __builtin_amdgcn_global_load_lds((const __attribute__((address_space(1))) void*)(gp), \
                                     (__attribute__((address_space(3))) void*)(lp), 16, 0, 0)

__device__ __forceinline__ unsigned ldsoff(const void* p) {
    return (unsigned)(size_t)(const __attribute__((address_space(3))) void*)p;
}

#define DSR(dst, base, off) asm volatile("ds_read_b128 %0, %1 offset:" off : "=v"(dst) : "v"(base))
#define VM(n) asm volatile("s_waitcnt vmcnt(" #n ")" ::: "memory")
#define BAR __builtin_amdgcn_s_barrier()
#define SCB __builtin_amdgcn_sched_barrier(0)

// single required fence (rule #18): SCB between lgkmcnt(0) and MFMA
#define PH_OPEN  BAR; asm volatile("s_waitcnt lgkmcnt(0)" ::: "memory"); SCB; \
                 __builtin_amdgcn_s_setprio(1);
#define PH_CLOSE __builtin_amdgcn_s_setprio(0);

// ---------------- merged RMSNorm + fp16 split ----------------
// rows 0..8191: x -> Acat [hi|lo]; rows 8192..12287: slot_embeds -> Bcat [hi|hi]
__global__ void rmsnorm_both(const float* __restrict__ x, const float* __restrict__ ng,
                             const float* __restrict__ semb, const float* __restrict__ sg,
                             unsigned short* __restrict__ Acat, unsigned short* __restrict__ Bcat) {
    int row = blockIdx.x;
    int t = threadIdx.x;
    const bool isX = row < NB*SEQ;
    const float* in = isX ? x + (size_t)row * DIM : semb + (size_t)(row - NB*SEQ) * DIM;
    const float* gamma = isX ? ng : sg;
    unsigned short* rb = isX ? Acat + (size_t)row * 2048
                             : Bcat + (size_t)(row - NB*SEQ) * 2048;
    float4 v = reinterpret_cast<const float4*>(in)[t];
    float ss = v.x*v.x + v.y*v.y + v.z*v.z + v.w*v.w;
    #pragma unroll
    for (int off = 32; off >= 1; off >>= 1) ss += __shfl_down(ss, off, 64);
    __shared__ float red[4];
    if ((t & 63) == 0) red[t >> 6] = ss;
    __syncthreads();
    float inv = RMS_SCALE / fmaxf(sqrtf(red[0] + red[1] + red[2] + red[3]), 1e-12f);
    float4 g = reinterpret_cast<const float4*>(gamma)[t];
    float f[4] = {v.x*inv*g.x, v.y*inv*g.y, v.z*inv*g.z, v.w*inv*g.w};
    us4 hv, lv;
    #pragma unroll
    for (int q = 0; q < 4; ++q) {
        unsigned short h = f2h(f[q]);
        hv[q] = h;
        lv[q] = isX ? f2h(f[q] - h2f(h)) : h;
    }
    *reinterpret_cast<us4*>(&rb[t*4]) = hv;
    *reinterpret_cast<us4*>(&rb[1024 + t*4]) = lv;
}

// ---------------- merged max-partial reduce (rows + cols) ----------------
__global__ void maxreduce_all(const float* __restrict__ rowpM, const float* __restrict__ colpM,
                              float* __restrict__ rmax, float* __restrict__ cmax) {
    int bx = blockIdx.x, t = threadIdx.x;
    if (bx < 32) {
        int row = bx * 256 + t;
        float m = -INFINITY;
        for (int p = 0; p < 64; ++p) m = fmaxf(m, rowpM[(size_t)p*8192 + row]);
        rmax[row] = m;
    } else {
        int fl = (bx - 32) * 256 + t;      // 0..8191 = b*4096 + col
        int b = fl >> 12, col = fl & 4095;
        float m = -INFINITY;
        for (int p = b*32; p < b*32 + 32; ++p) m = fmaxf(m, colpM[(size_t)p*4096 + col]);
        cmax[fl] = m;
    }
}

// ---------------- merged sum-partial reduce ----------------
__global__ void sumreduce_all(const float* __restrict__ rowpS, const float* __restrict__ colpS,
                              float* __restrict__ rinv, float* __restrict__ cinv) {
    int bx = blockIdx.x, t = threadIdx.x;
    const float* src = (bx < 32) ? rowpS : colpS;
    float* dst = (bx < 32) ? rinv : cinv;
    int fl = (bx & 31) * 256 + t;
    float s = 0.f;
    for (int p = 0; p < 128; ++p) s += src[(size_t)p*8192 + fl];
    dst[fl] = 1.0f / s;
}

// ---------------- fused weights pass: unnormalized exp (fp16) + sum partials ----------------
__global__ void make_weights(const float* __restrict__ logits,
                             const float* __restrict__ cmax, const float* __restrict__ rmax,
                             unsigned short* __restrict__ comb, unsigned short* __restrict__ dispT,
                             float* __restrict__ rowpS, float* __restrict__ colpS) {
    int b = blockIdx.z;
    const float* L = logits + (size_t)b * SEQ * ES;
    int n0 = blockIdx.y * 32, e0 = blockIdx.x * 32;
    int t = threadIdx.x;
    int r = t >> 3, c4 = (t & 7) * 4;
    __shared__ unsigned short tile[32][36];
    float4 v = *reinterpret_cast<const float4*>(&L[(size_t)(n0 + r) * ES + e0 + c4]);
    float rm = rmax[b*SEQ + n0 + r];
    float vv[4] = {v.x, v.y, v.z, v.w};
    us4 cb;
    float rs = 0.f;
    #pragma unroll
    for (int q = 0; q < 4; ++q) {
        cb[q] = f2h(__expf(vv[q] - rm));
        rs += h2f(cb[q]);
        float dv = __expf(vv[q] - cmax[b*ES + e0 + c4 + q]);
        tile[c4 + q][r] = f2h(dv);
    }
    *reinterpret_cast<us4*>(&comb[(size_t)b*SEQ*ES + (size_t)(n0 + r)*ES + e0 + c4]) = cb;
    rs += __shfl_xor(rs, 1, 64);
    rs += __shfl_xor(rs, 2, 64);
    rs += __shfl_xor(rs, 4, 64);
    if ((t & 7) == 0)
        rowpS[(size_t)blockIdx.x * 8192 + b*SEQ + n0 + r] = rs;
    __syncthreads();
    us4 o = *reinterpret_cast<us4*>(&tile[t >> 3][(t & 7) * 4]);
    *reinterpret_cast<us4*>(&dispT[(size_t)b*ES*SEQ + (size_t)(e0 + (t >> 3))*SEQ + n0 + (t & 7)*4]) = o;
    float cs = h2f(o[0]) + h2f(o[1]) + h2f(o[2]) + h2f(o[3]);
    cs += __shfl_xor(cs, 1, 64);
    cs += __shfl_xor(cs, 2, 64);
    cs += __shfl_xor(cs, 4, 64);
    if ((t & 7) == 0)
        colpS[(size_t)blockIdx.y * 8192 + b*ES + e0 + (t >> 3)] = cs;
}

// ---------------- 16-bit transpose (dtype-agnostic) ----------------
__global__ void transpose_b16(const unsigned short* __restrict__ src, unsigned short* __restrict__ dst,
                              int sld, int dld, long sStride, long dStride) {
    int z = blockIdx.z;
    const unsigned short* S = src + (size_t)z * sStride;
    unsigned short* D = dst + (size_t)z * dStride;
    int r0 = blockIdx.y * 32, c0 = blockIdx.x * 32;
    int t = threadIdx.x;
    __shared__ unsigned short tile[32][36];
    us4 v = *reinterpret_cast<const us4*>(&S[(size_t)(r0 + (t>>3)) * sld + c0 + (t&7)*4]);
    #pragma unroll
    for (int q = 0; q < 4; ++q) tile[(t&7)*4 + q][t>>3] = v[q];
    __syncthreads();
    us4 o = *reinterpret_cast<us4*>(&tile[t >> 3][(t & 7) * 4]);
    *reinterpret_cast<us4*>(&D[(size_t)(c0 + (t>>3)) * dld + r0 + (t&7)*4]) = o;
}

// ---------------- f32 -> fp16 transpose ----------------
__global__ void transpose_f32_h16(const float* __restrict__ src, unsigned short* __restrict__ dst,
                                  int sld, int dld, long sStride, long dStride) {
    int z = blockIdx.z;
    const float* S = src + (size_t)z * sStride;
    unsigned short* D = dst + (size_t)z * dStride;
    int r0 = blockIdx.y * 32, c0 = blockIdx.x * 32;
    int t = threadIdx.x;
    __shared__ unsigned short tile[32][36];
    float4 v = *reinterpret_cast<const float4*>(&S[(size_t)(r0 + (t>>3)) * sld + c0 + (t&7)*4]);
    float vv[4] = {v.x, v.y, v.z, v.w};
    #pragma unroll
    for (int q = 0; q < 4; ++q) tile[(t&7)*4 + q][t>>3] = f2h(vv[q]);
    __syncthreads();
    us4 o = *reinterpret_cast<us4*>(&tile[t >> 3][(t & 7) * 4]);
    *reinterpret_cast<us4*>(&D[(size_t)(c0 + (t>>3)) * dld + r0 + (t&7)*4]) = o;
}

// ================= 256x256 8-phase MFMA GEMM — r4 core, fp16 16x16x32 =================
// Stage map: P1,P2: A(t+1)->b1; P3,P4: B(t+2)->b0; P5,P6: A(t+2)->b0; P7,P8: B(t+3)->b1.
// vmcnt(4)@P4 and @P8. Tail drains vmcnt(0). STATS=1: max-only softmax partials.
template<int EPI, int OM, int STATS>
__global__ __launch_bounds__(512, 2)
void mfma_gemm256(const unsigned short* __restrict__ A, const unsigned short* __restrict__ B,
                  void* __restrict__ Cv, const float* __restrict__ bias,
                  int N, int K, int lda, int ldb, int ldc,
                  long aStride, long bStride, long cStride, int bMod,
                  float* __restrict__ rowpM, float* __restrict__ colpM) {
    __shared__ unsigned short lds[65536];   // 128 KB
    const int t = threadIdx.x;
    const int lane = t & 63, wave = t >> 6;
    const int wr = wave >> 2, wc = wave & 3;
    const int z = blockIdx.z, zb = z % bMod;
    const unsigned short* Ab = A + (size_t)z * aStride;
    const unsigned short* Bb = B + (size_t)zb * bStride;
    const int gx = gridDim.x;
    int flat = blockIdx.x + blockIdx.y * gx;
    const int cpx = (gx * gridDim.y) >> 3;
    flat = (flat & 7) * cpx + (flat >> 3);
    const int m0 = (flat / gx) * 256, n0 = (flat % gx) * 256;

    const int sr = t >> 3;
    const int sg = (t & 7) ^ (sr & 7);
    const unsigned short* gA = Ab + (size_t)(m0 + sr) * lda + sg * 8;
    const unsigned short* gB = Bb + (size_t)(n0 + sr) * ldb + sg * 8;
    unsigned short* ldsw = lds + wave * 512;

    const int lr = lane & 15, lk = lane >> 4;
    const unsigned sw0 = (unsigned)(((lk)     ^ (lr & 7)) << 4);
    const unsigned sw1 = (unsigned)(((4 + lk) ^ (lr & 7)) << 4);
    const unsigned l0  = ldsoff(lds);
    const unsigned arow = (unsigned)((wr*128 + lr) * 128);
    const unsigned brow = (unsigned)((wc*64  + lr) * 128);
    const unsigned ab00 = l0 + arow + sw0,          ab10 = l0 + arow + sw1;
    const unsigned bb00 = l0 + 32768 + brow + sw0,  bb10 = l0 + 32768 + brow + sw1;
    const unsigned ab01 = ab00 + 65536, ab11 = ab10 + 65536;
    const unsigned bb01 = bb00 + 65536, bb11 = bb10 + 65536;

    #define STAGE_A(buf, half, tt) do { \
        const unsigned short* _g = gA + (size_t)((half)*128) * lda + (size_t)(tt)*64; \
        unsigned short* _l = ldsw + (buf)*32768 + (half)*8192; \
        GLOAD_LDS16(_g, _l); \
        GLOAD_LDS16(_g + (size_t)64*lda, _l + 4096); } while(0)
    #define STAGE_B(buf, half, tt) do { \
        const unsigned short* _g = gB + (size_t)((half)*128) * ldb + (size_t)(tt)*64; \
        unsigned short* _l = ldsw + (buf)*32768 + 16384 + (half)*8192; \
        GLOAD_LDS16(_g, _l); \
        GLOAD_LDS16(_g + (size_t)64*ldb, _l + 4096); } while(0)

    #define MFMA16(MB, CN) \
        _Pragma("unroll") \
        for (int m = 0; m < 4; ++m) { \
            _Pragma("unroll") \
            for (int n = 0; n < 2; ++n) { \
                acc[(MB)+m][(CN)+n] = __builtin_amdgcn_mfma_f32_16x16x32_f16(a0[m], b0[(CN)+n], acc[(MB)+m][(CN)+n], 0, 0, 0); \
                acc[(MB)+m][(CN)+n] = __builtin_amdgcn_mfma_f32_16x16x32_f16(a1[m], b1[(CN)+n], acc[(MB)+m][(CN)+n], 0, 0, 0); \
            } \
        }

    f32x4 acc[8][4] = {};
    f16x8 a0[4], a1[4], b0[4], b1[4];
    const int NT = K / 64;

    STAGE_B(0, 0, 0); STAGE_B(0, 1, 0);
    STAGE_A(0, 0, 0); STAGE_A(0, 1, 0);
    STAGE_B(1, 0, 1); STAGE_B(1, 1, 1);
    VM(4); BAR;

    for (int tt = 0; tt < NT; tt += 2) {
        const bool pf = (tt + 2 < NT);
        // P1
        DSR(a0[0], ab00, "0");    DSR(a0[1], ab00, "2048");
        DSR(a0[2], ab00, "4096"); DSR(a0[3], ab00, "6144");
        DSR(a1[0], ab10, "0");    DSR(a1[1], ab10, "2048");
        DSR(a1[2], ab10, "4096"); DSR(a1[3], ab10, "6144");
        DSR(b0[0], bb00, "0");    DSR(b0[1], bb00, "2048");
        DSR(b1[0], bb10, "0");    DSR(b1[1], bb10, "2048");
        STAGE_A(1, 0, tt+1);
        PH_OPEN MFMA16(0, 0) PH_CLOSE
        BAR;
        // P2
        DSR(b0[2], bb00, "4096"); DSR(b0[3], bb00, "6144");
        DSR(b1[2], bb10, "4096"); DSR(b1[3], bb10, "6144");
        STAGE_A(1, 1, tt+1);
        PH_OPEN MFMA16(0, 2) PH_CLOSE
        BAR;
        // P3
        DSR(a0[0], ab00, "8192");  DSR(a0[1], ab00, "10240");
        DSR(a0[2], ab00, "12288"); DSR(a0[3], ab00, "14336");
        DSR(a1[0], ab10, "8192");  DSR(a1[1], ab10, "10240");
        DSR(a1[2], ab10, "12288"); DSR(a1[3], ab10, "14336");
        if (pf) STAGE_B(0, 0, tt+2);
        PH_OPEN MFMA16(4, 0) PH_CLOSE
        BAR;
        // P4 + wait
        if (pf) STAGE_B(0, 1, tt+2);
        PH_OPEN MFMA16(4, 2) PH_CLOSE
        if (pf) { VM(4); } else { VM(0); }
        BAR;
        // P5
        DSR(a0[0], ab01, "0");    DSR(a0[1], ab01, "2048");
        DSR(a0[2], ab01, "4096"); DSR(a0[3], ab01, "6144");
        DSR(a1[0], ab11, "0");    DSR(a1[1], ab11, "2048");
        DSR(a1[2], ab11, "4096"); DSR(a1[3], ab11, "6144");
        DSR(b0[0], bb01, "0");    DSR(b0[1], bb01, "2048");
        DSR(b1[0], bb11, "0");    DSR(b1[1], bb11, "2048");
        if (pf) STAGE_A(0, 0, tt+2);
        PH_OPEN MFMA16(0, 0) PH_CLOSE
        BAR;
        // P6
        DSR(b0[2], bb01, "4096"); DSR(b0[3], bb01, "6144");
        DSR(b1[2], bb11, "4096"); DSR(b1[3], bb11, "6144");
        if (pf) STAGE_A(0, 1, tt+2);
        PH_OPEN MFMA16(0, 2) PH_CLOSE
        BAR;
        // P7
        DSR(a0[0], ab01, "8192");  DSR(a0[1], ab01, "10240");
        DSR(a0[2], ab01, "12288"); DSR(a0[3], ab01, "14336");
        DSR(a1[0], ab11, "8192");  DSR(a1[1], ab11, "10240");
        DSR(a1[2], ab11, "12288"); DSR(a1[3], ab11, "14336");
        if (pf) STAGE_B(1, 0, tt+3);
        PH_OPEN MFMA16(4, 0) PH_CLOSE
        BAR;
        // P8 + wait
        if (pf) STAGE_B(1, 1, tt+3);
        PH_OPEN MFMA16(4, 2) PH_CLOSE
        if (pf) { VM(4); } else { VM(0); }
        BAR;
    }

    if (STATS) {
        #pragma unroll
        for (int f = 0; f < 8; ++f) {
            #pragma unroll
            for (int r = 0; r < 4; ++r) {
                float m = fmaxf(fmaxf(acc[f][0][r], acc[f][1][r]), fmaxf(acc[f][2][r], acc[f][3][r]));
                #pragma unroll
                for (int msk = 1; msk <= 8; msk <<= 1) m = fmaxf(m, __shfl_xor(m, msk, 64));
                if ((lane & 15) == 0) {
                    int row = m0 + wr*128 + f*16 + (lane>>4)*4 + r;
                    int slot = (n0 >> 6) + wc;
                    rowpM[(size_t)slot*8192 + row] = m;
                }
            }
        }
        #pragma unroll
        for (int n = 0; n < 4; ++n) {
            float m = -INFINITY;
            #pragma unroll
            for (int f = 0; f < 8; ++f)
                #pragma unroll
                for (int r = 0; r < 4; ++r) m = fmaxf(m, acc[f][n][r]);
            m = fmaxf(m, __shfl_xor(m, 16, 64));
            m = fmaxf(m, __shfl_xor(m, 32, 64));
            if ((lane >> 4) == 0) {
                int col = n0 + wc*64 + n*16 + lane;
                int slot = (m0 >> 7) + wr;
                colpM[(size_t)slot*4096 + col] = m;
            }
        }
    }

    const float* bz = (EPI != 0) ? bias + (size_t)zb * N : nullptr;
    long coff = (long)z * cStride;
    int rbase = (lane >> 4) * 4;
    int cbase = lane & 15;
    #pragma unroll
    for (int f = 0; f < 8; ++f) {
        #pragma unroll
        for (int n = 0; n < 4; ++n) {
            int col  = n0 + wc*64 + n*16 + cbase;
            int row0 = m0 + wr*128 + f*16 + rbase;
            float bv = (EPI != 0) ? bz[col] : 0.f;
            float vals[4];
            #pragma unroll
            for (int r = 0; r < 4; ++r) {
                float v = acc[f][n][r] + bv;
                if (EPI == 2) v = gelu_exact(v);
                vals[r] = v;
            }
            if (OM == 0) {
                float* C = (float*)Cv + coff;
                #pragma unroll
                for (int r = 0; r < 4; ++r) C[(size_t)(row0 + r) * ldc + col] = vals[r];
            } else {
                unsigned short* C = (unsigned short*)Cv + coff;
                #pragma unroll
                for (int r = 0; r < 4; ++r) C[(size_t)(row0 + r) * ldc + col] = f2h(vals[r]);
            }
        }
    }
    #undef STAGE_A
    #undef STAGE_B
    #undef MFMA16
}

// ================= 256x128 8-phase MFMA GEMM — fp16, quad halves, vmcnt(4)@P4/P8 ==========
template<int EPI, int OM, int SC>
__global__ __launch_bounds__(512, 2)
void mfma_gemmX(const unsigned short* __restrict__ A, const unsigned short* __restrict__ B,
                void* __restrict__ Cv, const float* __restrict__ bias,
                int N, int K, int lda, int ldb, int ldc,
                long aStride, long bStride, long cStride, long cStrideE, int bMod,
                const float* __restrict__ svec) {
    __shared__ unsigned short lds[49152];   // 96 KB
    const int t = threadIdx.x;
    const int lane = t & 63, wave = t >> 6;
    const int wr = wave >> 2, wc = wave & 3;
    const int z = blockIdx.z, zb = z % bMod;
    const unsigned short* Ab = A + (size_t)z * aStride;
    const unsigned short* Bb = B + (size_t)zb * bStride;
    const int gx = gridDim.x;
    int flat = blockIdx.x + blockIdx.y * gx;
    const int cpx = (gx * gridDim.y) >> 3;
    flat = (flat & 7) * cpx + (flat >> 3);
    const int m0 = (flat / gx) * 256, n0 = (flat % gx) * 128;

    const int sr = t >> 3;
    const int sg = (t & 7) ^ (sr & 7);
    const unsigned short* gA = Ab + (size_t)(m0 + sr) * lda + sg * 8;
    const unsigned short* gB = Bb + (size_t)(n0 + sr) * ldb + sg * 8;
    unsigned short* ldsw = lds + wave * 512;

    const int lr = lane & 15, lk = lane >> 4;
    const unsigned g0 = (unsigned)(((lk)     ^ (lr & 7)) << 4);
    const unsigned g1 = (unsigned)(((4 + lk) ^ (lr & 7)) << 4);
    const unsigned l0 = ldsoff(lds);
    const unsigned arow = (unsigned)((wr*64 + lr) * 128);
    const unsigned brow = (unsigned)((wc*32 + lr) * 128);
    const unsigned ax00 = l0 + arow + g0,          ax10 = l0 + arow + g1;
    const unsigned bx00 = l0 + 32768 + brow + g0,  bx10 = l0 + 32768 + brow + g1;
    const unsigned ax01 = ax00 + 49152, ax11 = ax10 + 49152;
    const unsigned bx01 = bx00 + 49152, bx11 = bx10 + 49152;

    #define STAGE_AX(buf, quad, tt) do { \
        const unsigned short* _g = gA + (size_t)((quad)*64) * lda + (size_t)(tt)*64; \
        unsigned short* _l = ldsw + (buf)*24576 + (quad)*8192; \
        GLOAD_LDS16(_g, _l); \
        GLOAD_LDS16(_g + (size_t)128*lda, _l + 4096); } while(0)
    #define STAGE_BX(buf, tt) do { \
        const unsigned short* _g = gB + (size_t)(tt)*64; \
        unsigned short* _l = ldsw + (buf)*24576 + 16384; \
        GLOAD_LDS16(_g, _l); \
        GLOAD_LDS16(_g + (size_t)64*ldb, _l + 4096); } while(0)

    #define MFMA8(MB, AR, BR) \
        _Pragma("unroll") \
        for (int m = 0; m < 4; ++m) { \
            _Pragma("unroll") \
            for (int n = 0; n < 2; ++n) { \
                acc[(MB)+m][n] = __builtin_amdgcn_mfma_f32_16x16x32_f16(AR[m], BR[n], acc[(MB)+m][n], 0, 0, 0); \
            } \
        }

    f32x4 acc[8][2] = {};
    f16x8 a0[4], a1[4], b0[2], b1[2];
    const int NT = K / 64;

    STAGE_AX(0, 0, 0); STAGE_BX(0, 0); STAGE_AX(0, 1, 0);
    STAGE_AX(1, 0, 1); STAGE_BX(1, 1);
    VM(0); BAR;

    for (int tt = 0; tt < NT; tt += 2) {
        const bool pf2 = (tt + 2 < NT);
        const bool pf3 = (tt + 3 < NT);
        // P1
        DSR(a0[0], ax00, "0");    DSR(a0[1], ax00, "2048");
        DSR(a0[2], ax00, "4096"); DSR(a0[3], ax00, "6144");
        DSR(b0[0], bx00, "0");    DSR(b0[1], bx00, "2048");
        STAGE_AX(1, 1, tt+1);
        PH_OPEN MFMA8(0, a0, b0) PH_CLOSE
        BAR;
        // P2
        DSR(a1[0], ax10, "0");    DSR(a1[1], ax10, "2048");
        DSR(a1[2], ax10, "4096"); DSR(a1[3], ax10, "6144");
        DSR(b1[0], bx10, "0");    DSR(b1[1], bx10, "2048");
        PH_OPEN MFMA8(0, a1, b1) PH_CLOSE
        BAR;
        // P3
        DSR(a0[0], ax00, "16384"); DSR(a0[1], ax00, "18432");
        DSR(a0[2], ax00, "20480"); DSR(a0[3], ax00, "22528");
        if (pf2) STAGE_AX(0, 0, tt+2);
        PH_OPEN MFMA8(4, a0, b0) PH_CLOSE
        BAR;
        // P4 + wait
        DSR(a1[0], ax10, "16384"); DSR(a1[1], ax10, "18432");
        DSR(a1[2], ax10, "20480"); DSR(a1[3], ax10, "22528");
        if (pf2) STAGE_BX(0, tt+2);
        PH_OPEN MFMA8(4, a1, b1) PH_CLOSE
        if (pf2) { VM(4); } else { VM(0); }
        BAR;
        // P5
        DSR(a0[0], ax01, "0");    DSR(a0[1], ax01, "2048");
        DSR(a0[2], ax01, "4096"); DSR(a0[3], ax01, "6144");
        DSR(b0[0], bx01, "0");    DSR(b0[1], bx01, "2048");
        if (pf2) STAGE_AX(0, 1, tt+2);
        PH_OPEN MFMA8(0, a0, b0) PH_CLOSE
        BAR;
        // P6
        DSR(a1[0], ax11, "0");    DSR(a1[1], ax11, "2048");
        DSR(a1[2], ax11, "4096"); DSR(a1[3], ax11, "6144");
        DSR(b1[0], bx11, "0");    DSR(b1[1], bx11, "2048");
        PH_OPEN MFMA8(0, a1, b1) PH_CLOSE
        BAR;
        // P7
        DSR(a0[0], ax01, "16384"); DSR(a0[1], ax01, "18432");
        DSR(a0[2], ax01, "20480"); DSR(a0[3], ax01, "22528");
        if (pf3) STAGE_AX(1, 0, tt+3);
        PH_OPEN MFMA8(4, a0, b0) PH_CLOSE
        BAR;
        // P8 + wait
        DSR(a1[0], ax11, "16384"); DSR(a1[1], ax11, "18432");
        DSR(a1[2], ax11, "20480"); DSR(a1[3], ax11, "22528");
        if (pf3) STAGE_BX(1, tt+3);
        PH_OPEN MFMA8(4, a1, b1) PH_CLOSE
        if (pf3) { VM(4); } else { VM(0); }
        BAR;
    }

    const float* bz = (EPI != 0) ? bias + (size_t)zb * N : nullptr;
    const float* sv = SC ? svec + (size_t)z * 4096 : nullptr;
    long coff = (long)z * cStride + (long)zb * cStrideE;
    int rbase = (lane >> 4) * 4;
    int cbase = lane & 15;
    #pragma unroll
    for (int f = 0; f < 8; ++f) {
        #pragma unroll
        for (int n = 0; n < 2; ++n) {
            int col  = n0 + wc*32 + n*16 + cbase;
            int row0 = m0 + wr*128 + f*16 + rbase;
            float bv = (EPI != 0) ? bz[col] : 0.f;
            float vals[4];
            #pragma unroll
            for (int r = 0; r < 4; ++r) {
                float v = acc[f][n][r] + bv;
                if (SC) v *= sv[row0 + r];
                if (EPI == 2) v = gelu_exact(v);
                vals[r] = v;
            }
            if (OM == 0) {
                float* C = (float*)Cv + coff;
                #pragma unroll
                for (int r = 0; r < 4; ++r) C[(size_t)(row0 + r) * ldc + col] = vals[r];
            } else if (OM == 1) {
                unsigned short* C = (unsigned short*)Cv + coff;
                #pragma unroll
                for (int r = 0; r < 4; ++r) C[(size_t)(row0 + r) * ldc + col] = f2h(vals[r]);
            } else {
                unsigned short* C = (unsigned short*)Cv + coff;
                us4 o;
                #pragma unroll
                for (int r = 0; r < 4; ++r) o[r] = f2h(vals[r]);
                *reinterpret_cast<us4*>(&C[(size_t)col * ldc + row0]) = o;
            }
        }
    }
    #undef STAGE_AX
    #undef STAGE_BX
    #undef MFMA8
}

extern "C" void kernel_launch(void* const* d_in, const int* in_sizes, int n_in,
                              void* d_out, int out_size, void* d_ws, size_t ws_size,
                              hipStream_t stream) {
    const float* x    = (const float*)d_in[0];
    const float* ng   = (const float*)d_in[1];
    const float* sg   = (const float*)d_in[2];
    const float* semb = (const float*)d_in[3];
    const float* w1   = (const float*)d_in[4];
    const float* b1   = (const float*)d_in[5];
    const float* w2   = (const float*)d_in[6];
    const float* b2   = (const float*)d_in[7];
    float* out = (float*)d_out;

    // ---- workspace layout (r12 exact) ----
    char* base = (char*)d_ws;
    unsigned short* Acat  = (unsigned short*)(base);               // [8192][2048] fp16 [hi|lo]
    unsigned short* Bcat  = (unsigned short*)(base + 33554432);    // [4096][2048] fp16 [hi|hi]
    unsigned short* dispT = (unsigned short*)(base);               // [2][4096][4096] (step5+)
    unsigned short* w2T   = (unsigned short*)(base);               // [8][1024][4096] (step9+, dispT dead)
    float*          logits= (float*)(base + 75497472);             // [2][4096][4096] f32
    unsigned short* hbuf  = (unsigned short*)(base + 75497472);    // [16][512][4096] fp16 (step10+, logits dead)
    unsigned short* w1T   = (unsigned short*)(base + 142606336);   // [8][4096][1024] fp16 (step7+)
    unsigned short* xnT   = (unsigned short*)(base + 209715200);   // [2][1024][4096]
    unsigned short* comb  = (unsigned short*)(base + 226492416);   // [2][4096][4096]
    unsigned short* slots = (unsigned short*)(base + 293601280);   // [2][4096][1024]
    unsigned short* eoT   = (unsigned short*)(base + 293601280);   // [2][1024][4096] (reuses slots)
    float* rowpM = (float*)(base + 226492416);        // [64][8192] (comb region, dead)
    float* colpM = rowpM + 64*8192;                   // [64][4096]
    float* rmax  = (float*)(base + 310378496);
    float* rinv  = rmax + 8192;
    float* cmax  = rinv + 8192;
    float* cinv  = cmax + 8192;
    float* rowpS = cinv + 8192;                       // [128][8192]
    float* colpS = rowpS + 128*8192;                  // [128][8192]

    // 1. merged RMSNorm + fp16 split
    rmsnorm_both<<<NB*SEQ + NEXP*NSLOT, 256, 0, stream>>>(x, ng, semb, sg, Acat, Bcat);

    // 2. xnT[b][d][n] (hi half of Acat)
    transpose_b16<<<dim3(DIM/32, SEQ/32, NB), 256, 0, stream>>>(
        Acat, xnT, 2048, SEQ, (long)SEQ*2048, (long)DIM*SEQ);

    // 3. logits = [x_hi|x_lo] @ [s_hi|s_hi]^T  (fp16 2-term split, K=2048) + max partials
    mfma_gemm256<0,0,1><<<dim3(ES/256, (NB*SEQ)/256, 1), 512, 0, stream>>>(
        Acat, Bcat, logits, nullptr, ES, 2048, 2048, 2048, ES,
        0L, 0L, 0L, 1, rowpM, colpM);

    // 4. merged max reductions
    maxreduce_all<<<64, 256, 0, stream>>>(rowpM, colpM, rmax, cmax);

    // 5. comb_u + dispT_u (fp16 unnormalized) + sum partials
    make_weights<<<dim3(ES/32, SEQ/32, NB), 256, 0, stream>>>(
        logits, cmax, rmax, comb, dispT, rowpS, colpS);

    // 6. merged sum reductions -> rinv, cinv
    sumreduce_all<<<64, 256, 0, stream>>>(rowpS, colpS, rinv, cinv);

    // 7. w1T (fp16)
    transpose_f32_h16<<<dim3(HID/32, DIM/32, NEXP), 256, 0, stream>>>(
        w1, w1T, HID, DIM, (long)DIM*HID, (long)HID*DIM);

    // 8. slots = (dispT_u @ xnT^T) * cinv[es]
    mfma_gemmX<0,1,1><<<dim3(DIM/128, ES/256, NB), 512, 0, stream>>>(
        dispT, xnT, slots, nullptr, DIM, SEQ, SEQ, SEQ, DIM,
        (long)ES*SEQ, (long)DIM*SEQ, (long)ES*DIM, 0L, NB, cinv);

    // 9. w2T (fp16)
    transpose_f32_h16<<<dim3(DIM/32, HID/32, NEXP), 256, 0, stream>>>(
        w2, w2T, DIM, HID, (long)HID*DIM, (long)DIM*HID);

    // 10. FF1: h = gelu(slots @ w1T^T + b1)
    mfma_gemm256<2,1,0><<<dim3(HID/256, NSLOT/256, NB*NEXP), 512, 0, stream>>>(
        slots, w1T, hbuf, b1, HID, DIM, DIM, DIM, HID,
        (long)NSLOT*DIM, (long)HID*DIM, (long)NSLOT*HID, NEXP,
        nullptr, nullptr);

    // 11. FF2: eoT = (h @ w2T^T + b2)^T
    mfma_gemmX<1,2,0><<<dim3(DIM/128, NSLOT/256, NB*NEXP), 512, 0, stream>>>(
        hbuf, w2T, eoT, b2, DIM, HID, HID, HID, ES,
        (long)NSLOT*HID, (long)DIM*HID, (long)(DIM*ES/NEXP), (long)(NSLOT - DIM*ES/NEXP), NEXP,
        nullptr);

    // 12. out = (comb_u @ eoT^T) * rinv[n]
    mfma_gemmX<0,0,1><<<dim3(DIM/128, SEQ/256, NB), 512, 0, stream>>>(
        comb, eoT, out, nullptr, DIM, ES, ES, ES, DIM,
        (long)SEQ*ES, (long)DIM*ES, (long)SEQ*DIM, 0L, NB, rinv);
}